// Round 14
// baseline (129.572 us; speedup 1.0000x reference)
//
#include <hip/hip_runtime.h>

// ---------------------------------------------------------------------------
// GPT-2 style MHA block: qkv = x@W_attn+b; causal softmax(QK^T)V; out@W_proj+b
// B=1, S=4096, D=768, H=12, HD=64.  All heavy math in bf16 MFMA (fp32 accum).
// Attention: split-K flash decoding, 32x32x16 MFMA, 4 waves x 32 q-rows.
// Round 12: K/V staged via global_load_lds with PRE-SWIZZLED SOURCE (rule #21:
// linear LDS dest + inverse-swizzled global src + swz8 read = r9's exact LDS
// bytes).  Kb/Vt double-buffered, Vr single (wave-private transpose), ONE
// lgkmcnt-only barrier per tile; per-wave vmcnt drain before barrier.
// (r11 lesson: K-from-global gathers 64 cache lines/instr — LDS is required.)
// ---------------------------------------------------------------------------

typedef short bf16x8 __attribute__((ext_vector_type(8)));      // MFMA A/B frag
typedef float f32x16 __attribute__((ext_vector_type(16)));     // 32x32 C/D frag
typedef unsigned short u16x8_t __attribute__((ext_vector_type(8)));
typedef unsigned short u16x4_t __attribute__((ext_vector_type(4)));
typedef unsigned int   u32x4_t __attribute__((ext_vector_type(4)));
typedef float f32x4 __attribute__((ext_vector_type(4)));       // 16x16 C/D (gemm)

#define ATT_S  4096
#define ATT_D  768
#define ATT_3D 2304
#define ATT_H  12
#define LOG2E  1.44269504089f

__device__ __forceinline__ unsigned short f2b(float f) {
  union { float f; unsigned int u; } v; v.f = f;
  unsigned int r = v.u + 0x7fffu + ((v.u >> 16) & 1u);   // RNE
  return (unsigned short)(r >> 16);
}
__device__ __forceinline__ float b2f(unsigned short b) {
  union { unsigned int u; float f; } v; v.u = ((unsigned int)b) << 16;
  return v.f;
}
__device__ __forceinline__ unsigned int cvtpk(float a, float b) {
  unsigned int r;
  asm("v_cvt_pk_bf16_f32 %0, %1, %2" : "=v"(r) : "v"(a), "v"(b));
  return r;
}
__device__ __forceinline__ float m3(float a, float b, float c) {
  return fmaxf(fmaxf(a, b), c);               // clang fuses to v_max3_f32
}

__device__ __forceinline__ f32x4 mfma16(bf16x8 a, bf16x8 b, f32x4 c) {
  return __builtin_amdgcn_mfma_f32_16x16x32_bf16(a, b, c, 0, 0, 0);
}
__device__ __forceinline__ f32x16 mfma32(bf16x8 a, bf16x8 b, f32x16 c) {
  return __builtin_amdgcn_mfma_f32_32x32x16_bf16(a, b, c, 0, 0, 0);
}

__device__ __forceinline__ void glds16(const void* g, void* l) {
  __builtin_amdgcn_global_load_lds((__attribute__((address_space(1))) void*)g,
                                   (__attribute__((address_space(3))) void*)l,
                                   16, 0, 0);
}

// raw barrier: LDS ops complete, NO vmcnt drain here (callers drain their own
// vmcnt when they must publish gload_lds data across the barrier).
__device__ __forceinline__ void lbar() {
  asm volatile("s_waitcnt lgkmcnt(0)" ::: "memory");
  __builtin_amdgcn_s_barrier();
}
__device__ __forceinline__ void vdrain() {
  asm volatile("s_waitcnt vmcnt(0)" ::: "memory");
}

// 16B chunk c of row `row` in a pitch-64 bf16 LDS tile, XOR slot swizzle (T2).
__device__ __forceinline__ int swz8(int row, int c) {
  return row * 64 + ((c ^ (row & 7)) << 3);
}

// --------------------------- pre-pass kernels ------------------------------

__global__ __launch_bounds__(256) void convert_f32_bf16(
    const float* __restrict__ in, unsigned short* __restrict__ out, int n4) {
  int i = blockIdx.x * 256 + threadIdx.x;
  if (i >= n4) return;
  float4 v = ((const float4*)in)[i];
  u16x4_t o;
  o[0] = f2b(v.x); o[1] = f2b(v.y); o[2] = f2b(v.z); o[3] = f2b(v.w);
  ((u16x4_t*)out)[i] = o;
}

__global__ __launch_bounds__(256) void transpose_conv(
    const float* __restrict__ W, unsigned short* __restrict__ WT, int K, int N) {
  __shared__ float tile[32][33];
  int bx = blockIdx.x, by = blockIdx.y;
  int tx = threadIdx.x & 31, ty = threadIdx.x >> 5;
#pragma unroll
  for (int k = 0; k < 4; k++)
    tile[ty + k * 8][tx] = W[(size_t)(by * 32 + ty + k * 8) * N + bx * 32 + tx];
  __syncthreads();
#pragma unroll
  for (int k = 0; k < 4; k++)
    WT[(size_t)(bx * 32 + ty + k * 8) * K + by * 32 + tx] = f2b(tile[tx][ty + k * 8]);
}

// --------------------------- bf16 MFMA GEMM --------------------------------

template <int BF16_OUT>
__global__ __launch_bounds__(256) void gemm_bias(
    const unsigned short* __restrict__ A, const unsigned short* __restrict__ Bt,
    const float* __restrict__ bias, void* __restrict__ Cout,
    int M, int N, int K) {
  __shared__ unsigned short As[128 * 32];
  __shared__ unsigned short Bs[128 * 32];
  const int t = threadIdx.x;
  const int lane = t & 63;
  const int wave = t >> 6;
  const int wr = wave >> 1, wc = wave & 1;
  const int rl = lane & 15, rg = lane >> 4;

  const int nbn = N >> 7;
  const int nwg = gridDim.x;
  const int bid = blockIdx.x;
  const int cpx = nwg >> 3;
  const int swz = (bid & 7) * cpx + (bid >> 3);
  const int bm = swz / nbn, bn = swz % nbn;

  const unsigned short* Ab = A + (size_t)bm * 128 * K;
  const unsigned short* Bb = Bt + (size_t)bn * 128 * K;

  f32x4 acc[4][4];
#pragma unroll
  for (int m = 0; m < 4; m++)
#pragma unroll
    for (int n = 0; n < 4; n++) acc[m][n] = (f32x4){0.f, 0.f, 0.f, 0.f};

  for (int kt = 0; kt < K; kt += 32) {
    if (kt) __syncthreads();
#pragma unroll
    for (int it = 0; it < 2; ++it) {
      int idx = it * 256 + t;
      int row = idx >> 2;
      int slot = idx & 3;
      int sl2 = slot ^ ((row >> 1) & 3);
      unsigned short* ldsA = As + (size_t)(it * 256 + wave * 64) * 8;
      unsigned short* ldsB = Bs + (size_t)(it * 256 + wave * 64) * 8;
      glds16(Ab + (size_t)row * K + kt + sl2 * 8, ldsA);
      glds16(Bb + (size_t)row * K + kt + sl2 * 8, ldsB);
    }
    __syncthreads();

    bf16x8 a[4], b[4];
#pragma unroll
    for (int m = 0; m < 4; m++) {
      int row = wr * 64 + m * 16 + rl;
      int sl2 = rg ^ ((row >> 1) & 3);
      a[m] = *(const bf16x8*)&As[row * 32 + sl2 * 8];
    }
#pragma unroll
    for (int n = 0; n < 4; n++) {
      int row = wc * 64 + n * 16 + rl;
      int sl2 = rg ^ ((row >> 1) & 3);
      b[n] = *(const bf16x8*)&Bs[row * 32 + sl2 * 8];
    }
#pragma unroll
    for (int m = 0; m < 4; m++)
#pragma unroll
      for (int n = 0; n < 4; n++)
        acc[m][n] = mfma16(a[m], b[n], acc[m][n]);
  }

#pragma unroll
  for (int n = 0; n < 4; n++) {
    int col = bn * 128 + wc * 64 + n * 16 + rl;
    float bv = bias[col];
#pragma unroll
    for (int m = 0; m < 4; m++) {
      int row0 = bm * 128 + wr * 64 + m * 16 + rg * 4;
#pragma unroll
      for (int i = 0; i < 4; i++) {
        float v = acc[m][n][i] + bv;
        if (BF16_OUT)
          ((unsigned short*)Cout)[(size_t)(row0 + i) * N + col] = f2b(v);
        else
          ((float*)Cout)[(size_t)(row0 + i) * N + col] = v;
      }
    }
  }
}

// --------------------------- flash attention (split-K, 32x32) --------------
// Unit = (head, 128-row q-strip, chunk of <=16 KV tiles).  960 = 12 x 80,
// longest-first.  4 waves x 32 q-rows.  gload_lds staging, dbuf Kb/Vt,
// single Vr, one barrier per tile.  P in registers via cvt_pk + shfl(32).

__global__ __launch_bounds__(256) void attn_fwd(
    const unsigned short* __restrict__ qkv, unsigned short* __restrict__ aout,
    unsigned short* __restrict__ pscr, float* __restrict__ ml) {
  __shared__ unsigned short Kb[2][64 * 64];   // K rows [key][hd], swz bytes (16KB)
  __shared__ unsigned short Vt[2][64 * 64];   // V^T    [hd][key], swz bytes (16KB)
  __shared__ unsigned short Vr[64 * 64];      // V rows staging (8KB, wave-private)

  const int tid = threadIdx.x;
  const int lane = tid & 63;
  const int w = tid >> 6;
  const int l31 = lane & 31, h5 = lane >> 5;

  const int bid = blockIdx.x;
  const int h = bid % ATT_H;
  const int u = 79 - (bid / ATT_H);           // long chunks dispatched first
  int sb, ck;
  if (u < 8)       { sb = u;                    ck = 0; }
  else if (u < 24) { sb = 8 + ((u - 8) >> 1);   ck = (u - 8) & 1; }
  else if (u < 48) { sb = 16 + (u - 24) / 3;    ck = (u - 24) % 3; }
  else             { sb = 24 + ((u - 48) >> 2); ck = (u - 48) & 3; }

  const int nt = 2 * sb + 2;                  // KV tiles for this strip
  const int t0 = ck * 16;                     // even -> buffer parity = t&1
  const int t1 = min(nt, t0 + 16);
  const int q = sb * 128 + w * 32 + l31;      // this lane's q row

  const int skey = tid >> 3;                  // staged key row (0..31, 2 passes)
  const int slotK = (tid & 7) ^ (skey & 7);   // inverse-swizzled SOURCE slot:
                                              // LDS[key][j] = glob[key][j^(key&7)]
  // Q fragments (full 64-hd row per lane, 4 frags of k=16)
  bf16x8 qf[4];
#pragma unroll
  for (int ks = 0; ks < 4; ks++)
    qf[ks] = *(const bf16x8*)&qkv[(size_t)q * ATT_3D + h * 64 + ks * 16 + h5 * 8];

  float mS = -3.0e38f, lS = 0.f;
  f32x16 oa0 = (f32x16)(0.f), oa1 = (f32x16)(0.f);   // O^T hd-groups 0/1

  const size_t gstep = (size_t)64 * ATT_3D;
  // per-lane K source offset within a tile (V = +768)
  const size_t gK = (size_t)skey * ATT_3D + 768 + h * 64 + slotK * 8;

  // prologue: stage tile t0 -> Kb[0], Vr; drain; transpose -> Vt[0]
  {
    const size_t gb = gK + (size_t)t0 * gstep;
    glds16(&qkv[gb],                       &Kb[0][w * 512]);
    glds16(&qkv[gb + 32 * ATT_3D],         &Kb[0][2048 + w * 512]);
    glds16(&qkv[gb + 768],                 &Vr[w * 512]);
    glds16(&qkv[gb + 32 * ATT_3D + 768],   &Vr[2048 + w * 512]);
    vdrain();
#pragma unroll
    for (int kk = 0; kk < 2; ++kk) {          // wave-private transpose
      int kb = w + kk * 4;
      u16x8_t g;
#pragma unroll
      for (int j = 0; j < 8; j++)
        g[j] = Vr[swz8(kb * 8 + j, lane >> 3) + (lane & 7)];
      *(u16x8_t*)&Vt[0][swz8(lane, kb)] = g;
    }
  }
  lbar();

  for (int t = t0; t < t1; ++t) {
    const int cur = t & 1;
    const bool pref = (t + 1 < t1);
    const bool active = (t * 64 <= sb * 128 + w * 32 + 31);
    if (pref) {                               // async stage t+1 (full-iter latency)
      const size_t gb = gK + (size_t)(t + 1) * gstep;
      glds16(&qkv[gb],                     &Kb[cur ^ 1][w * 512]);
      glds16(&qkv[gb + 32 * ATT_3D],       &Kb[cur ^ 1][2048 + w * 512]);
      glds16(&qkv[gb + 768],               &Vr[w * 512]);
      glds16(&qkv[gb + 32 * ATT_3D + 768], &Vr[2048 + w * 512]);
    }

    if (active) {
      // ---- S^T = K @ Q^T ----
      f32x16 st[2];
      st[0] = (f32x16)(0.f); st[1] = (f32x16)(0.f);
      __builtin_amdgcn_s_setprio(1);
#pragma unroll
      for (int kg = 0; kg < 2; kg++)
#pragma unroll
        for (int ks = 0; ks < 4; ks++) {
          bf16x8 kfr = *(const bf16x8*)&Kb[cur][swz8(kg * 32 + l31, ks * 2 + h5)];
          st[kg] = mfma32(kfr, qf[ks], st[kg]);
        }
      __builtin_amdgcn_s_setprio(0);

      if (t * 64 + 63 > sb * 128 + w * 32) {  // causal mask
#pragma unroll
        for (int kg = 0; kg < 2; kg++)
#pragma unroll
          for (int r = 0; r < 16; r++) {
            int key = t * 64 + kg * 32 + (r & 3) + 8 * (r >> 2) + 4 * h5;
            if (key > q) st[kg][r] = -3.0e38f;
          }
      }

      // ---- online softmax: max3 tree + 1 cross-half shuffle ----
      float a = m3(st[0][0], st[0][1], st[0][2]);
      float b = m3(st[0][3], st[0][4], st[0][5]);
      float c = m3(st[0][6], st[0][7], st[0][8]);
      float d = m3(st[0][9], st[0][10], st[0][11]);
      float e = m3(st[0][12], st[0][13], st[0][14]);
      float f = m3(st[0][15], st[1][0], st[1][1]);
      float g2 = m3(st[1][2], st[1][3], st[1][4]);
      float h2 = m3(st[1][5], st[1][6], st[1][7]);
      float i2 = m3(st[1][8], st[1][9], st[1][10]);
      float j2 = m3(st[1][11], st[1][12], st[1][13]);
      float k2 = fmaxf(st[1][14], st[1][15]);
      float pm = m3(m3(a, b, c), m3(d, e, f), m3(g2, h2, i2));
      pm = m3(pm, j2, k2);
      pm = fmaxf(pm, __shfl_xor(pm, 32, 64));
      if (!__all(pm - mS <= 8.f)) {           // defer-max: rescale rarely
        float mn = fmaxf(mS, pm);
        float fac = __expf(mS - mn);
        mS = mn;
        lS *= fac;
#pragma unroll
        for (int r = 0; r < 16; r++) { oa0[r] *= fac; oa1[r] *= fac; }
      }
      const float mC = mS * LOG2E;
      float ps0 = 0.f, ps1 = 0.f;
#pragma unroll
      for (int kg = 0; kg < 2; kg++)
#pragma unroll
        for (int r = 0; r < 16; r++) {
          float p = __builtin_amdgcn_exp2f(fmaf(st[kg][r], LOG2E, -mC));
          st[kg][r] = p;
          if (r & 1) ps1 += p; else ps0 += p;
        }
      float psum = ps0 + ps1;
      psum += __shfl_xor(psum, 32, 64);
      lS += psum;

      // ---- P assembly (registers only) + PV ----
      __builtin_amdgcn_s_setprio(1);
#pragma unroll
      for (int kc = 0; kc < 4; kc++) {
        const int kg = kc >> 1;
        const int rb = (kc & 1) << 3;
        unsigned e00 = cvtpk(st[kg][rb + 0], st[kg][rb + 1]);  // octet 2kc
        unsigned e01 = cvtpk(st[kg][rb + 2], st[kg][rb + 3]);
        unsigned e10 = cvtpk(st[kg][rb + 4], st[kg][rb + 5]);  // octet 2kc+1
        unsigned e11 = cvtpk(st[kg][rb + 6], st[kg][rb + 7]);
        unsigned own0 = h5 ? e10 : e00, own1 = h5 ? e11 : e01;
        unsigned snd0 = h5 ? e00 : e10, snd1 = h5 ? e01 : e11;
        unsigned r0 = (unsigned)__shfl_xor((int)snd0, 32, 64);
        unsigned r1 = (unsigned)__shfl_xor((int)snd1, 32, 64);
        u32x4_t fd;
        fd[0] = h5 ? r0 : own0; fd[1] = h5 ? r1 : own1;
        fd[2] = h5 ? own0 : r0; fd[3] = h5 ? own1 : r1;
        bf16x8 pfr = __builtin_bit_cast(bf16x8, fd);
        bf16x8 v0 = *(const bf16x8*)&Vt[cur][swz8(l31, kc * 2 + h5)];
        bf16x8 v1 = *(const bf16x8*)&Vt[cur][swz8(32 + l31, kc * 2 + h5)];
        oa0 = mfma32(v0, pfr, oa0);
        oa1 = mfma32(v1, pfr, oa1);
      }
      __builtin_amdgcn_s_setprio(0);
    }

    if (pref) {                               // publish t+1: drain own gloads,
      vdrain();                               // wave-private V transpose
#pragma unroll
      for (int kk = 0; kk < 2; ++kk) {
        int kb = w + kk * 4;
        u16x8_t g;
#pragma unroll
        for (int j = 0; j < 8; j++)
          g[j] = Vr[swz8(kb * 8 + j, lane >> 3) + (lane & 7)];
        *(u16x8_t*)&Vt[cur ^ 1][swz8(lane, kb)] = g;
      }
    }
    lbar();                                   // ONE barrier per tile
  }

  // ---- epilogue: write normalized O (final or partial) ----
  const bool split = (sb >= 8);
  unsigned short* dst;
  if (!split || ck == 0) {
    dst = aout + (size_t)q * ATT_D + h * 64;
  } else {
    int sbase = (sb < 16) ? (sb - 8)
              : (sb < 24) ? 8 + (sb - 16) * 2
                          : 24 + (sb - 24) * 3;
    int s = h * 48 + sbase + (ck - 1);
    dst = pscr + (size_t)s * 8192 + (w * 32 + l31) * 64;
  }
  if (split && lane < 32) {                   // (m,l) per q-row, once
    int b2 = (sb < 16) ? (sb - 8) * 2
           : (sb < 24) ? 16 + (sb - 16) * 3
                       : 40 + (sb - 24) * 4;
    float2* mlp = (float2*)ml;
    mlp[(size_t)(h * 72 + b2 + ck) * 128 + w * 32 + lane] = make_float2(mS, lS);
  }
  const float inv = 1.f / lS;
#pragma unroll
  for (int hg = 0; hg < 2; hg++)
#pragma unroll
    for (int rq = 0; rq < 4; rq++) {
      u16x4_t o4;
#pragma unroll
      for (int c = 0; c < 4; c++) {
        float v = (hg ? oa1[rq * 4 + c] : oa0[rq * 4 + c]) * inv;
        o4[c] = f2b(v);
      }
      *(u16x4_t*)&dst[hg * 32 + rq * 8 + h5 * 4] = o4;
    }
}

// --------------------------- split-K combine -------------------------------
// One block per split strip (h, sb>=8): 288 = 12 x 24.  256 thr: (q, colhalf).

__global__ __launch_bounds__(256) void attn_combine(
    const unsigned short* __restrict__ pscr, const float* __restrict__ ml,
    unsigned short* __restrict__ ao) {
  const int unit = blockIdx.x;
  const int h = unit / 24, sb = unit % 24 + 8;
  const int nch = (sb < 16) ? 2 : (sb < 24) ? 3 : 4;
  const int tid = threadIdx.x;
  const int qr = tid >> 1, part = tid & 1;    // q-row 0..127, col half 0..1

  const int b2 = (sb < 16) ? (sb - 8) * 2
               : (sb < 24) ? 16 + (sb - 16) * 3
                           : 40 + (sb - 24) * 4;
  const int sbase = (sb < 16) ? (sb - 8)
                  : (sb < 24) ? 8 + (sb - 16) * 2
                              : 24 + (sb - 24) * 3;

  const float2* mlp = (const float2*)ml;
  float m[4], l[4];
  float M = -3.0e38f;
  for (int c = 0; c < nch; ++c) {
    float2 p = mlp[(size_t)(h * 72 + b2 + c) * 128 + qr];
    m[c] = p.x; l[c] = p.y;
    M = fmaxf(M, m[c]);
  }
  float wgt[4], den = 0.f;
  for (int c = 0; c < nch; ++c) {
    wgt[c] = l[c] * __expf(m[c] - M);
    den += wgt[c];
  }

  float acc[32];
#pragma unroll
  for (int j = 0; j < 32; j++) acc[j] = 0.f;

  unsigned short* aorow =
      ao + (size_t)(sb * 128 + qr) * ATT_D + h * 64 + part * 32;
  for (int c = 0; c < nch; ++c) {
    const unsigned short* src =
        (c == 0) ? aorow
                 : pscr + (size_t)(h * 48 + sbase + (c - 1)) * 8192 +
                       qr * 64 + part * 32;
#pragma unroll
    for (int v = 0; v < 4; v++) {
      u16x8_t x = *(const u16x8_t*)(src + v * 8);
#pragma unroll
      for (int j = 0; j < 8; j++) acc[v * 8 + j] += wgt[c] * b2f(x[j]);
    }
  }
  float invd = 1.f / den;
#pragma unroll
  for (int v = 0; v < 4; v++) {
    u16x8_t o;
#pragma unroll
    for (int j = 0; j < 8; j++) o[j] = f2b(acc[v * 8 + j] * invd);
    *(u16x8_t*)(aorow + v * 8) = o;
  }
}

// ------------------------------- launcher ----------------------------------

extern "C" void kernel_launch(void* const* d_in, const int* in_sizes, int n_in,
                              void* d_out, int out_size, void* d_ws, size_t ws_size,
                              hipStream_t stream) {
  const float* x      = (const float*)d_in[0];
  const float* W_attn = (const float*)d_in[1];
  const float* b_attn = (const float*)d_in[2];
  const float* W_proj = (const float*)d_in[3];
  const float* b_proj = (const float*)d_in[4];
  float* out = (float*)d_out;

  char* ws = (char*)d_ws;
  unsigned short* xb  = (unsigned short*)(ws);              //  6,291,456 B
  unsigned short* WaT = (unsigned short*)(ws + 6291456);    //  3,538,944 B
  unsigned short* WpT = (unsigned short*)(ws + 9830400);    //  1,179,648 B
  unsigned short* qkv = (unsigned short*)(ws + 11010048);   // 18,874,368 B
  unsigned short* ao  = (unsigned short*)(ws + 29884416);   //  6,291,456 B
  // split-K scratch (aliases regions dead during attention):
  unsigned short* pscr = (unsigned short*)(ws);             // 576 x 16KB slots
  float*          ml   = (float*)(ws + 9830400);            // 884,736 B (WpT)

  convert_f32_bf16<<<3072, 256, 0, stream>>>(x, xb, 786432);
  transpose_conv<<<dim3(72, 24), 256, 0, stream>>>(W_attn, WaT, 768, 2304);

  gemm_bias<1><<<576, 256, 0, stream>>>(xb, WaT, b_attn, qkv, 4096, 2304, 768);
  attn_fwd<<<960, 256, 0, stream>>>(qkv, ao, pscr, ml);
  attn_combine<<<288, 256, 0, stream>>>(pscr, ml, ao);

  // WpT region doubled as ml during attention; transpose W_proj only now.
  transpose_conv<<<dim3(24, 24), 256, 0, stream>>>(W_proj, WpT, 768, 768);
  gemm_bias<0><<<192, 256, 0, stream>>>(ao, WpT, b_proj, out, 4096, 768, 768);
}

// Round 15
// 129.340 us; speedup vs baseline: 1.0018x; 1.0018x over previous
//
#include <hip/hip_runtime.h>

// ---------------------------------------------------------------------------
// GPT-2 style MHA block: qkv = x@W_attn+b; causal softmax(QK^T)V; out@W_proj+b
// B=1, S=4096, D=768, H=12, HD=64.  All heavy math in bf16 MFMA (fp32 accum).
// Attention: split-K flash decoding, 32x32x16 MFMA, 4 waves x 32 q-rows.
// Round 12: K/V staged via global_load_lds with PRE-SWIZZLED SOURCE (rule #21:
// linear LDS dest + inverse-swizzled global src + swz8 read = r9's exact LDS
// bytes).  Kb/Vt double-buffered, Vr single (wave-private transpose), ONE
// lgkmcnt-only barrier per tile; per-wave vmcnt drain before barrier.
// (r11 lesson: K-from-global gathers 64 cache lines/instr — LDS is required.)
// ---------------------------------------------------------------------------

typedef short bf16x8 __attribute__((ext_vector_type(8)));      // MFMA A/B frag
typedef float f32x16 __attribute__((ext_vector_type(16)));     // 32x32 C/D frag
typedef unsigned short u16x8_t __attribute__((ext_vector_type(8)));
typedef unsigned short u16x4_t __attribute__((ext_vector_type(4)));
typedef unsigned int   u32x4_t __attribute__((ext_vector_type(4)));
typedef float f32x4 __attribute__((ext_vector_type(4)));       // 16x16 C/D (gemm)

#define ATT_S  4096
#define ATT_D  768
#define ATT_3D 2304
#define ATT_H  12
#define LOG2E  1.44269504089f

__device__ __forceinline__ unsigned short f2b(float f) {
  union { float f; unsigned int u; } v; v.f = f;
  unsigned int r = v.u + 0x7fffu + ((v.u >> 16) & 1u);   // RNE
  return (unsigned short)(r >> 16);
}
__device__ __forceinline__ float b2f(unsigned short b) {
  union { unsigned int u; float f; } v; v.u = ((unsigned int)b) << 16;
  return v.f;
}
__device__ __forceinline__ unsigned int cvtpk(float a, float b) {
  unsigned int r;
  asm("v_cvt_pk_bf16_f32 %0, %1, %2" : "=v"(r) : "v"(a), "v"(b));
  return r;
}
__device__ __forceinline__ float m3(float a, float b, float c) {
  return fmaxf(fmaxf(a, b), c);               // clang fuses to v_max3_f32
}

__device__ __forceinline__ f32x4 mfma16(bf16x8 a, bf16x8 b, f32x4 c) {
  return __builtin_amdgcn_mfma_f32_16x16x32_bf16(a, b, c, 0, 0, 0);
}
__device__ __forceinline__ f32x16 mfma32(bf16x8 a, bf16x8 b, f32x16 c) {
  return __builtin_amdgcn_mfma_f32_32x32x16_bf16(a, b, c, 0, 0, 0);
}

__device__ __forceinline__ void glds16(const void* g, void* l) {
  __builtin_amdgcn_global_load_lds((__attribute__((address_space(1))) void*)g,
                                   (__attribute__((address_space(3))) void*)l,
                                   16, 0, 0);
}

// raw barrier: LDS ops complete, NO vmcnt drain here (callers drain their own
// vmcnt when they must publish gload_lds data across the barrier).
__device__ __forceinline__ void lbar() {
  asm volatile("s_waitcnt lgkmcnt(0)" ::: "memory");
  __builtin_amdgcn_s_barrier();
}
__device__ __forceinline__ void vdrain() {
  asm volatile("s_waitcnt vmcnt(0)" ::: "memory");
}

// 16B chunk c of row `row` in a pitch-64 bf16 LDS tile, XOR slot swizzle (T2).
__device__ __forceinline__ int swz8(int row, int c) {
  return row * 64 + ((c ^ (row & 7)) << 3);
}

// --------------------------- pre-pass kernels ------------------------------

__global__ __launch_bounds__(256) void convert_f32_bf16(
    const float* __restrict__ in, unsigned short* __restrict__ out, int n4) {
  int i = blockIdx.x * 256 + threadIdx.x;
  if (i >= n4) return;
  float4 v = ((const float4*)in)[i];
  u16x4_t o;
  o[0] = f2b(v.x); o[1] = f2b(v.y); o[2] = f2b(v.z); o[3] = f2b(v.w);
  ((u16x4_t*)out)[i] = o;
}

__global__ __launch_bounds__(256) void transpose_conv(
    const float* __restrict__ W, unsigned short* __restrict__ WT, int K, int N) {
  __shared__ float tile[32][33];
  int bx = blockIdx.x, by = blockIdx.y;
  int tx = threadIdx.x & 31, ty = threadIdx.x >> 5;
#pragma unroll
  for (int k = 0; k < 4; k++)
    tile[ty + k * 8][tx] = W[(size_t)(by * 32 + ty + k * 8) * N + bx * 32 + tx];
  __syncthreads();
#pragma unroll
  for (int k = 0; k < 4; k++)
    WT[(size_t)(bx * 32 + ty + k * 8) * K + by * 32 + tx] = f2b(tile[tx][ty + k * 8]);
}

// --------------------------- bf16 MFMA GEMM --------------------------------

template <int BF16_OUT>
__global__ __launch_bounds__(256) void gemm_bias(
    const unsigned short* __restrict__ A, const unsigned short* __restrict__ Bt,
    const float* __restrict__ bias, void* __restrict__ Cout,
    int M, int N, int K) {
  __shared__ unsigned short As[128 * 32];
  __shared__ unsigned short Bs[128 * 32];
  const int t = threadIdx.x;
  const int lane = t & 63;
  const int wave = t >> 6;
  const int wr = wave >> 1, wc = wave & 1;
  const int rl = lane & 15, rg = lane >> 4;

  const int nbn = N >> 7;
  const int nwg = gridDim.x;
  const int bid = blockIdx.x;
  const int cpx = nwg >> 3;
  const int swz = (bid & 7) * cpx + (bid >> 3);
  const int bm = swz / nbn, bn = swz % nbn;

  const unsigned short* Ab = A + (size_t)bm * 128 * K;
  const unsigned short* Bb = Bt + (size_t)bn * 128 * K;

  f32x4 acc[4][4];
#pragma unroll
  for (int m = 0; m < 4; m++)
#pragma unroll
    for (int n = 0; n < 4; n++) acc[m][n] = (f32x4){0.f, 0.f, 0.f, 0.f};

  for (int kt = 0; kt < K; kt += 32) {
    if (kt) __syncthreads();
#pragma unroll
    for (int it = 0; it < 2; ++it) {
      int idx = it * 256 + t;
      int row = idx >> 2;
      int slot = idx & 3;
      int sl2 = slot ^ ((row >> 1) & 3);
      unsigned short* ldsA = As + (size_t)(it * 256 + wave * 64) * 8;
      unsigned short* ldsB = Bs + (size_t)(it * 256 + wave * 64) * 8;
      glds16(Ab + (size_t)row * K + kt + sl2 * 8, ldsA);
      glds16(Bb + (size_t)row * K + kt + sl2 * 8, ldsB);
    }
    __syncthreads();

    bf16x8 a[4], b[4];
#pragma unroll
    for (int m = 0; m < 4; m++) {
      int row = wr * 64 + m * 16 + rl;
      int sl2 = rg ^ ((row >> 1) & 3);
      a[m] = *(const bf16x8*)&As[row * 32 + sl2 * 8];
    }
#pragma unroll
    for (int n = 0; n < 4; n++) {
      int row = wc * 64 + n * 16 + rl;
      int sl2 = rg ^ ((row >> 1) & 3);
      b[n] = *(const bf16x8*)&Bs[row * 32 + sl2 * 8];
    }
#pragma unroll
    for (int m = 0; m < 4; m++)
#pragma unroll
      for (int n = 0; n < 4; n++)
        acc[m][n] = mfma16(a[m], b[n], acc[m][n]);
  }

#pragma unroll
  for (int n = 0; n < 4; n++) {
    int col = bn * 128 + wc * 64 + n * 16 + rl;
    float bv = bias[col];
#pragma unroll
    for (int m = 0; m < 4; m++) {
      int row0 = bm * 128 + wr * 64 + m * 16 + rg * 4;
#pragma unroll
      for (int i = 0; i < 4; i++) {
        float v = acc[m][n][i] + bv;
        if (BF16_OUT)
          ((unsigned short*)Cout)[(size_t)(row0 + i) * N + col] = f2b(v);
        else
          ((float*)Cout)[(size_t)(row0 + i) * N + col] = v;
      }
    }
  }
}

// --------------------------- flash attention (split-K, 32x32) --------------
// Unit = (head, 128-row q-strip, chunk of <=16 KV tiles).  960 = 12 x 80,
// longest-first.  4 waves x 32 q-rows.  gload_lds staging, dbuf Kb/Vt,
// single Vr, one barrier per tile.  P in registers via cvt_pk + shfl(32).

__global__ __launch_bounds__(256) void attn_fwd(
    const unsigned short* __restrict__ qkv, unsigned short* __restrict__ aout,
    unsigned short* __restrict__ pscr, float* __restrict__ ml) {
  __shared__ unsigned short Kb[2][64 * 64];   // K rows [key][hd], swz bytes (16KB)
  __shared__ unsigned short Vt[2][64 * 64];   // V^T    [hd][key], swz bytes (16KB)
  __shared__ unsigned short Vr[64 * 64];      // V rows staging (8KB, wave-private)

  const int tid = threadIdx.x;
  const int lane = tid & 63;
  const int w = tid >> 6;
  const int l31 = lane & 31, h5 = lane >> 5;

  const int bid = blockIdx.x;
  const int h = bid % ATT_H;
  const int u = 79 - (bid / ATT_H);           // long chunks dispatched first
  int sb, ck;
  if (u < 8)       { sb = u;                    ck = 0; }
  else if (u < 24) { sb = 8 + ((u - 8) >> 1);   ck = (u - 8) & 1; }
  else if (u < 48) { sb = 16 + (u - 24) / 3;    ck = (u - 24) % 3; }
  else             { sb = 24 + ((u - 48) >> 2); ck = (u - 48) & 3; }

  const int nt = 2 * sb + 2;                  // KV tiles for this strip
  const int t0 = ck * 16;                     // even -> buffer parity = t&1
  const int t1 = min(nt, t0 + 16);
  const int q = sb * 128 + w * 32 + l31;      // this lane's q row

  const int skey = tid >> 3;                  // staged key row (0..31, 2 passes)
  const int slotK = (tid & 7) ^ (skey & 7);   // inverse-swizzled SOURCE slot:
                                              // LDS[key][j] = glob[key][j^(key&7)]
  // Q fragments (full 64-hd row per lane, 4 frags of k=16)
  bf16x8 qf[4];
#pragma unroll
  for (int ks = 0; ks < 4; ks++)
    qf[ks] = *(const bf16x8*)&qkv[(size_t)q * ATT_3D + h * 64 + ks * 16 + h5 * 8];

  float mS = -3.0e38f, lS = 0.f;
  f32x16 oa0 = (f32x16)(0.f), oa1 = (f32x16)(0.f);   // O^T hd-groups 0/1

  const size_t gstep = (size_t)64 * ATT_3D;
  // per-lane K source offset within a tile (V = +768)
  const size_t gK = (size_t)skey * ATT_3D + 768 + h * 64 + slotK * 8;

  // prologue: stage tile t0 -> Kb[0], Vr; drain; transpose -> Vt[0]
  {
    const size_t gb = gK + (size_t)t0 * gstep;
    glds16(&qkv[gb],                       &Kb[0][w * 512]);
    glds16(&qkv[gb + 32 * ATT_3D],         &Kb[0][2048 + w * 512]);
    glds16(&qkv[gb + 768],                 &Vr[w * 512]);
    glds16(&qkv[gb + 32 * ATT_3D + 768],   &Vr[2048 + w * 512]);
    vdrain();
#pragma unroll
    for (int kk = 0; kk < 2; ++kk) {          // wave-private transpose
      int kb = w + kk * 4;
      u16x8_t g;
#pragma unroll
      for (int j = 0; j < 8; j++)
        g[j] = Vr[swz8(kb * 8 + j, lane >> 3) + (lane & 7)];
      *(u16x8_t*)&Vt[0][swz8(lane, kb)] = g;
    }
  }
  lbar();

  for (int t = t0; t < t1; ++t) {
    const int cur = t & 1;
    const bool pref = (t + 1 < t1);
    const bool active = (t * 64 <= sb * 128 + w * 32 + 31);
    if (pref) {                               // async stage t+1 (full-iter latency)
      const size_t gb = gK + (size_t)(t + 1) * gstep;
      glds16(&qkv[gb],                     &Kb[cur ^ 1][w * 512]);
      glds16(&qkv[gb + 32 * ATT_3D],       &Kb[cur ^ 1][2048 + w * 512]);
      glds16(&qkv[gb + 768],               &Vr[w * 512]);
      glds16(&qkv[gb + 32 * ATT_3D + 768], &Vr[2048 + w * 512]);
    }

    if (active) {
      // ---- S^T = K @ Q^T ----
      f32x16 st[2];
      st[0] = (f32x16)(0.f); st[1] = (f32x16)(0.f);
      __builtin_amdgcn_s_setprio(1);
#pragma unroll
      for (int kg = 0; kg < 2; kg++)
#pragma unroll
        for (int ks = 0; ks < 4; ks++) {
          bf16x8 kfr = *(const bf16x8*)&Kb[cur][swz8(kg * 32 + l31, ks * 2 + h5)];
          st[kg] = mfma32(kfr, qf[ks], st[kg]);
        }
      __builtin_amdgcn_s_setprio(0);

      if (t * 64 + 63 > sb * 128 + w * 32) {  // causal mask
#pragma unroll
        for (int kg = 0; kg < 2; kg++)
#pragma unroll
          for (int r = 0; r < 16; r++) {
            int key = t * 64 + kg * 32 + (r & 3) + 8 * (r >> 2) + 4 * h5;
            if (key > q) st[kg][r] = -3.0e38f;
          }
      }

      // ---- online softmax: max3 tree + 1 cross-half shuffle ----
      float a = m3(st[0][0], st[0][1], st[0][2]);
      float b = m3(st[0][3], st[0][4], st[0][5]);
      float c = m3(st[0][6], st[0][7], st[0][8]);
      float d = m3(st[0][9], st[0][10], st[0][11]);
      float e = m3(st[0][12], st[0][13], st[0][14]);
      float f = m3(st[0][15], st[1][0], st[1][1]);
      float g2 = m3(st[1][2], st[1][3], st[1][4]);
      float h2 = m3(st[1][5], st[1][6], st[1][7]);
      float i2 = m3(st[1][8], st[1][9], st[1][10]);
      float j2 = m3(st[1][11], st[1][12], st[1][13]);
      float k2 = fmaxf(st[1][14], st[1][15]);
      float pm = m3(m3(a, b, c), m3(d, e, f), m3(g2, h2, i2));
      pm = m3(pm, j2, k2);
      pm = fmaxf(pm, __shfl_xor(pm, 32, 64));
      if (!__all(pm - mS <= 8.f)) {           // defer-max: rescale rarely
        float mn = fmaxf(mS, pm);
        float fac = __expf(mS - mn);
        mS = mn;
        lS *= fac;
#pragma unroll
        for (int r = 0; r < 16; r++) { oa0[r] *= fac; oa1[r] *= fac; }
      }
      const float mC = mS * LOG2E;
      float ps0 = 0.f, ps1 = 0.f;
#pragma unroll
      for (int kg = 0; kg < 2; kg++)
#pragma unroll
        for (int r = 0; r < 16; r++) {
          float p = __builtin_amdgcn_exp2f(fmaf(st[kg][r], LOG2E, -mC));
          st[kg][r] = p;
          if (r & 1) ps1 += p; else ps0 += p;
        }
      float psum = ps0 + ps1;
      psum += __shfl_xor(psum, 32, 64);
      lS += psum;

      // ---- P assembly (registers only) + PV ----
      __builtin_amdgcn_s_setprio(1);
#pragma unroll
      for (int kc = 0; kc < 4; kc++) {
        const int kg = kc >> 1;
        const int rb = (kc & 1) << 3;
        unsigned e00 = cvtpk(st[kg][rb + 0], st[kg][rb + 1]);  // octet 2kc
        unsigned e01 = cvtpk(st[kg][rb + 2], st[kg][rb + 3]);
        unsigned e10 = cvtpk(st[kg][rb + 4], st[kg][rb + 5]);  // octet 2kc+1
        unsigned e11 = cvtpk(st[kg][rb + 6], st[kg][rb + 7]);
        unsigned own0 = h5 ? e10 : e00, own1 = h5 ? e11 : e01;
        unsigned snd0 = h5 ? e00 : e10, snd1 = h5 ? e01 : e11;
        unsigned r0 = (unsigned)__shfl_xor((int)snd0, 32, 64);
        unsigned r1 = (unsigned)__shfl_xor((int)snd1, 32, 64);
        u32x4_t fd;
        fd[0] = h5 ? r0 : own0; fd[1] = h5 ? r1 : own1;
        fd[2] = h5 ? own0 : r0; fd[3] = h5 ? own1 : r1;
        bf16x8 pfr = __builtin_bit_cast(bf16x8, fd);
        bf16x8 v0 = *(const bf16x8*)&Vt[cur][swz8(l31, kc * 2 + h5)];
        bf16x8 v1 = *(const bf16x8*)&Vt[cur][swz8(32 + l31, kc * 2 + h5)];
        oa0 = mfma32(v0, pfr, oa0);
        oa1 = mfma32(v1, pfr, oa1);
      }
      __builtin_amdgcn_s_setprio(0);
    }

    if (pref) {                               // publish t+1: drain own gloads,
      vdrain();                               // wave-private V transpose
#pragma unroll
      for (int kk = 0; kk < 2; ++kk) {
        int kb = w + kk * 4;
        u16x8_t g;
#pragma unroll
        for (int j = 0; j < 8; j++)
          g[j] = Vr[swz8(kb * 8 + j, lane >> 3) + (lane & 7)];
        *(u16x8_t*)&Vt[cur ^ 1][swz8(lane, kb)] = g;
      }
    }
    lbar();                                   // ONE barrier per tile
  }

  // ---- epilogue: write normalized O (final or partial) ----
  const bool split = (sb >= 8);
  unsigned short* dst;
  if (!split || ck == 0) {
    dst = aout + (size_t)q * ATT_D + h * 64;
  } else {
    int sbase = (sb < 16) ? (sb - 8)
              : (sb < 24) ? 8 + (sb - 16) * 2
                          : 24 + (sb - 24) * 3;
    int s = h * 48 + sbase + (ck - 1);
    dst = pscr + (size_t)s * 8192 + (w * 32 + l31) * 64;
  }
  if (split && lane < 32) {                   // (m,l) per q-row, once
    int b2 = (sb < 16) ? (sb - 8) * 2
           : (sb < 24) ? 16 + (sb - 16) * 3
                       : 40 + (sb - 24) * 4;
    float2* mlp = (float2*)ml;
    mlp[(size_t)(h * 72 + b2 + ck) * 128 + w * 32 + lane] = make_float2(mS, lS);
  }
  const float inv = 1.f / lS;
#pragma unroll
  for (int hg = 0; hg < 2; hg++)
#pragma unroll
    for (int rq = 0; rq < 4; rq++) {
      u16x4_t o4;
#pragma unroll
      for (int c = 0; c < 4; c++) {
        float v = (hg ? oa1[rq * 4 + c] : oa0[rq * 4 + c]) * inv;
        o4[c] = f2b(v);
      }
      *(u16x4_t*)&dst[hg * 32 + rq * 8 + h5 * 4] = o4;
    }
}

// --------------------------- split-K combine -------------------------------
// One block per split strip (h, sb>=8): 288 = 12 x 24.  256 thr: (q, colhalf).

__global__ __launch_bounds__(256) void attn_combine(
    const unsigned short* __restrict__ pscr, const float* __restrict__ ml,
    unsigned short* __restrict__ ao) {
  const int unit = blockIdx.x;
  const int h = unit / 24, sb = unit % 24 + 8;
  const int nch = (sb < 16) ? 2 : (sb < 24) ? 3 : 4;
  const int tid = threadIdx.x;
  const int qr = tid >> 1, part = tid & 1;    // q-row 0..127, col half 0..1

  const int b2 = (sb < 16) ? (sb - 8) * 2
               : (sb < 24) ? 16 + (sb - 16) * 3
                           : 40 + (sb - 24) * 4;
  const int sbase = (sb < 16) ? (sb - 8)
                  : (sb < 24) ? 8 + (sb - 16) * 2
                              : 24 + (sb - 24) * 3;

  const float2* mlp = (const float2*)ml;
  float m[4], l[4];
  float M = -3.0e38f;
  for (int c = 0; c < nch; ++c) {
    float2 p = mlp[(size_t)(h * 72 + b2 + c) * 128 + qr];
    m[c] = p.x; l[c] = p.y;
    M = fmaxf(M, m[c]);
  }
  float wgt[4], den = 0.f;
  for (int c = 0; c < nch; ++c) {
    wgt[c] = l[c] * __expf(m[c] - M);
    den += wgt[c];
  }

  float acc[32];
#pragma unroll
  for (int j = 0; j < 32; j++) acc[j] = 0.f;

  unsigned short* aorow =
      ao + (size_t)(sb * 128 + qr) * ATT_D + h * 64 + part * 32;
  for (int c = 0; c < nch; ++c) {
    const unsigned short* src =
        (c == 0) ? aorow
                 : pscr + (size_t)(h * 48 + sbase + (c - 1)) * 8192 +
                       qr * 64 + part * 32;
#pragma unroll
    for (int v = 0; v < 4; v++) {
      u16x8_t x = *(const u16x8_t*)(src + v * 8);
#pragma unroll
      for (int j = 0; j < 8; j++) acc[v * 8 + j] += wgt[c] * b2f(x[j]);
    }
  }
  float invd = 1.f / den;
#pragma unroll
  for (int v = 0; v < 4; v++) {
    u16x8_t o;
#pragma unroll
    for (int j = 0; j < 8; j++) o[j] = f2b(acc[v * 8 + j] * invd);
    *(u16x8_t*)(aorow + v * 8) = o;
  }
}

// ------------------------------- launcher ----------------------------------

extern "C" void kernel_launch(void* const* d_in, const int* in_sizes, int n_in,
                              void* d_out, int out_size, void* d_ws, size_t ws_size,
                              hipStream_t stream) {
  const float* x      = (const float*)d_in[0];
  const float* W_attn = (const float*)d_in[1];
  const float* b_attn = (const float*)d_in[2];
  const float* W_proj = (const float*)d_in[3];
  const float* b_proj = (const float*)d_in[4];
  float* out = (float*)d_out;

  char* ws = (char*)d_ws;
  unsigned short* xb  = (unsigned short*)(ws);              //  6,291,456 B
  unsigned short* WaT = (unsigned short*)(ws + 6291456);    //  3,538,944 B
  unsigned short* WpT = (unsigned short*)(ws + 9830400);    //  1,179,648 B
  unsigned short* qkv = (unsigned short*)(ws + 11010048);   // 18,874,368 B
  unsigned short* ao  = (unsigned short*)(ws + 29884416);   //  6,291,456 B
  // split-K scratch (aliases regions dead during attention):
  unsigned short* pscr = (unsigned short*)(ws);             // 576 x 16KB slots
  float*          ml   = (float*)(ws + 9830400);            // 884,736 B (WpT)

  convert_f32_bf16<<<3072, 256, 0, stream>>>(x, xb, 786432);
  transpose_conv<<<dim3(72, 24), 256, 0, stream>>>(W_attn, WaT, 768, 2304);

  gemm_bias<1><<<576, 256, 0, stream>>>(xb, WaT, b_attn, qkv, 4096, 2304, 768);
  attn_fwd<<<960, 256, 0, stream>>>(qkv, ao, pscr, ml);
  attn_combine<<<288, 256, 0, stream>>>(pscr, ml, ao);

  // WpT region doubled as ml during attention; transpose W_proj only now.
  transpose_conv<<<dim3(24, 24), 256, 0, stream>>>(W_proj, WpT, 768, 768);
  gemm_bias<0><<<192, 256, 0, stream>>>(ao, WpT, b_proj, out, 4096, 768, 768);
}